// Round 17
// baseline (72.340 us; speedup 1.0000x reference)
//
#include <hip/hip_runtime.h>
#include <hip/hip_bf16.h>
#include <math.h>

#define Bsz 2
#define NHd 8
#define HD 32
#define CC 256
#define Himg 56
#define Wimg 56
#define SIMG 3136
#define NQtok 15
#define SS 3151           // SIMG + NQtok
#define SP 3200           // padded to 50*64
#define NWIN 50           // 49 image windows + 1 cls block
#define WN 49
#define MM 50             // mask dim
#define MROWS (Bsz*SP)    // 6400 padded token rows
#define NROWS (Bsz*SS)    // 6302 real rows

#define QSZ (Bsz*NHd*SP*HD)     // 1,638,400 elements per tensor
#define VSPSZ (Bsz*SIMG*CC)     // 1,605,632 (bf16)
#define USZ (MROWS*CC)          // 1,638,400 (bf16 U, padded rows)
#define WOTSZ (CC*CC)           // 65,536 (bf16 Wo^T)

typedef __attribute__((ext_vector_type(8))) short bf16x8;
typedef __attribute__((ext_vector_type(4))) float f32x4;

__device__ __forceinline__ short f2bf(float f) {
    __hip_bfloat16 h = __float2bfloat16(f);
    return *reinterpret_cast<short*>(&h);
}
__device__ __forceinline__ float bf2f(unsigned short s) {
    unsigned int u = ((unsigned int)s) << 16;
    return __uint_as_float(u);
}
__device__ __forceinline__ unsigned int pk2(float lo, float hi) {
    return ((unsigned int)(unsigned short)f2bf(hi) << 16)
         | (unsigned int)(unsigned short)f2bf(lo);
}
__device__ __forceinline__ bf16x8 cvt8(const float* p) {
    float4 a = *(const float4*)p, b = *(const float4*)(p + 4);
    bf16x8 o;
    o[0] = f2bf(a.x); o[1] = f2bf(a.y); o[2] = f2bf(a.z); o[3] = f2bf(a.w);
    o[4] = f2bf(b.x); o[5] = f2bf(b.y); o[6] = f2bf(b.z); o[7] = f2bf(b.w);
    return o;
}

// ---------------------------------------------------------------- QKV GEMM (fused prep)
// Grid (100 rowblocks x 12 colblocks). Block stages its A-tile (f32->bf16) and
// its W^T column tile into LDS, then 8 k-steps x 4 MFMA per wave.
// Blocks (rb<16, nb==0) additionally emit Wot = bf16(Wo^T) 64x64 tiles.
__global__ __launch_bounds__(256, 2) void qkv_fused(
        const float* __restrict__ x, const float* __restrict__ cls,
        const float* __restrict__ Wqkv, const float* __restrict__ bqkv,
        const float* __restrict__ Wo,
        short* __restrict__ Qbf, short* __restrict__ Kbf, short* __restrict__ Vtb,
        short* __restrict__ Vsp, short* __restrict__ Wot) {
    __shared__ __align__(16) short As[64][264];
    __shared__ __align__(16) short Wl[64][264];
    int tid = threadIdx.x;
    int w = tid >> 6, l = tid & 63, l15 = l & 15, hi = l >> 4;
    int rb = blockIdx.x, nb = blockIdx.y;
    int n0 = nb * 64;

    // stage A (64 rows x 256 cols, f32 -> bf16)
    #pragma unroll
    for (int p = 0; p < 8; p++) {
        int r = p * 8 + (tid >> 5);
        int c8 = (tid & 31) * 8;
        int row = rb * 64 + r;
        int b = row / SP, tok = row % SP;
        bf16x8 o = {0, 0, 0, 0, 0, 0, 0, 0};
        const float* pp = nullptr;
        if (tok < SIMG)      pp = x + (long)(b * SIMG + tok) * CC + c8;
        else if (tok < SS)   pp = cls + (long)(b * NQtok + tok - SIMG) * CC + c8;
        if (pp) o = cvt8(pp);
        *(bf16x8*)&As[r][c8] = o;
    }
    // stage W^T column tile
    {
        int n = tid & 63;
        #pragma unroll
        for (int i = 0; i < 8; i++) {
            int k0 = ((tid >> 6) + i * 4) * 8;
            bf16x8 o;
            #pragma unroll
            for (int j = 0; j < 8; j++) o[j] = f2bf(Wqkv[(long)(k0 + j) * 768 + n0 + n]);
            *(bf16x8*)&Wl[n][k0] = o;
        }
    }
    __syncthreads();

    f32x4 acc[4];
    #pragma unroll
    for (int t = 0; t < 4; t++) acc[t] = (f32x4){0.f, 0.f, 0.f, 0.f};
    #pragma unroll
    for (int k0 = 0; k0 < 256; k0 += 32) {
        bf16x8 a = *(const bf16x8*)&As[w * 16 + l15][k0 + hi * 8];
        #pragma unroll
        for (int t = 0; t < 4; t++) {
            bf16x8 bf = *(const bf16x8*)&Wl[t * 16 + l15][k0 + hi * 8];
            acc[t] = __builtin_amdgcn_mfma_f32_16x16x32_bf16(a, bf, acc[t], 0, 0, 0);
        }
    }
    float bias[4];
    #pragma unroll
    for (int t = 0; t < 4; t++) bias[t] = bqkv[n0 + t * 16 + l15];
    int which = nb >> 2;                  // 0=Q 1=K 2=V
    #pragma unroll
    for (int r = 0; r < 4; r++) {
        int row = rb * 64 + w * 16 + hi * 4 + r;
        int b = row / SP, tok = row % SP;
        int s;
        if (tok < SIMG) {
            int h = tok / Wimg, wq = tok % Wimg;
            s = (((h >> 3) * 7 + (wq >> 3)) << 6) | ((h & 7) << 3) | (wq & 7);
        } else s = tok;
        #pragma unroll
        for (int t = 0; t < 4; t++) {
            int n = n0 + t * 16 + l15;
            float v = acc[t][r] + bias[t];
            int cch = n & 255;
            int head = cch >> 5, d = cch & 31;
            long off = (((long)(b * NHd + head)) * SP + s) * HD + d;
            if (which == 0)      Qbf[off] = f2bf(v * 0.0625f);   // scale = 256^-0.5
            else if (which == 1) Kbf[off] = f2bf(v);
            else {
                short vb = f2bf(v);
                Vtb[(((long)(b * NHd + head)) * NWIN + (s >> 6)) * 2048
                    + d * 64 + (s & 63)] = vb;
                if (tok < SIMG) Vsp[(long)(b * SIMG + tok) * CC + cch] = vb;
            }
        }
    }

    // Wo^T emission (16 blocks): 64x64 LDS tile transpose, reusing As memory
    if (nb == 0 && rb < 16) {
        __syncthreads();
        float (*tile)[65] = (float (*)[65])As;
        int k0 = (rb & 3) * 64, n0w = (rb >> 2) * 64;
        int c = tid & 63, r0 = tid >> 6;
        #pragma unroll
        for (int p = 0; p < 16; p++) {
            int kl = p * 4 + r0;
            tile[kl][c] = Wo[(long)(k0 + kl) * CC + n0w + c];
        }
        __syncthreads();
        #pragma unroll
        for (int p = 0; p < 16; p++) {
            int nl = p * 4 + r0;
            Wot[(long)(n0w + nl) * CC + k0 + c] = f2bf(tile[c][nl]);
        }
    }
}

// ---------------------------------------------------------------- attention + LEPE
// Round-13 structure: block = (bh, qwin), 4 barrier-free waves; K AND V both
// prefetched one full window ahead (symmetrized pipeline). Swapped-operand
// QK^T + no-max flash, fused LEPE epilogue, bf16 U output.
__global__ __launch_bounds__(256, 2) void attn_mfma(
        const short* __restrict__ Qbf, const short* __restrict__ Kbf,
        const short* __restrict__ Vtb, const short* __restrict__ Vsp,
        const float* __restrict__ lepe_w, const float* __restrict__ lepe_b,
        const unsigned char* __restrict__ raw,
        short* __restrict__ U) {
    __shared__ __align__(16) unsigned int Pl[4][16][36];
    __shared__ float Ls[4][16];
    __shared__ float MAcc[4][16][32];

    int qb = blockIdx.x % NWIN;
    int bh = blockIdx.x / NWIN;
    int b = bh >> 3, head = bh & 7;
    int tid = threadIdx.x;
    int w = tid >> 6;
    int l = tid & 63;
    int l15 = l & 15;
    int hi = l >> 4;
    bool is_cls = (qb == WN);
    int qrow0 = is_cls ? 0 : w * 16;

    bf16x8 qf = *(const bf16x8*)&Qbf[((long)bh * SP + qb * 64 + qrow0 + l15) * HD + hi * 8];

    f32x4 acc0 = {0.f, 0.f, 0.f, 0.f};   // O[d=hi*4+reg][q=l15]
    f32x4 acc1 = {0.f, 0.f, 0.f, 0.f};   // O[d=16+hi*4+reg][q=l15]
    float l_run = 0.f;

    unsigned long long bits;
    if (!is_cls) {
        // inline mask canonicalization: bool bytes vs 4-byte layout
        bool isbool = (raw[2453] | raw[2457] | raw[2461]) != 0;
        bool mv = false;
        long e = (long)b * MM * MM + (long)qb * MM + l;
        if (isbool) {
            if (l < NWIN) mv = raw[e] != 0;
        } else {
            if (l < NWIN) mv = ((const unsigned int*)raw)[e] != 0;
        }
        bits = __ballot(l < NWIN && mv);
    } else {
        bits = (0x1111111111111ULL << w) & ((1ULL << 50) - 1);
    }

    int kb = __builtin_ctzll(bits);
    bits &= bits - 1;
    // prologue: load K AND V fragments of the first window
    long kbase0 = ((long)bh * SP + kb * 64) * HD;
    const short* Kp = Kbf + kbase0 + hi * 8;
    bf16x8 kc0 = *(const bf16x8*)(Kp + (0 * 16 + l15) * HD);
    bf16x8 kc1 = *(const bf16x8*)(Kp + (1 * 16 + l15) * HD);
    bf16x8 kc2 = *(const bf16x8*)(Kp + (2 * 16 + l15) * HD);
    bf16x8 kc3 = *(const bf16x8*)(Kp + (3 * 16 + l15) * HD);
    const short* Vp0 = Vtb + kbase0;
    bf16x8 va = *(const bf16x8*)&Vp0[l15 * 64 + hi * 8];
    bf16x8 vb = *(const bf16x8*)&Vp0[(16 + l15) * 64 + hi * 8];
    bf16x8 vc = *(const bf16x8*)&Vp0[l15 * 64 + 32 + hi * 8];
    bf16x8 vd = *(const bf16x8*)&Vp0[(16 + l15) * 64 + 32 + hi * 8];

    for (;;) {
        // QK^T swapped: s[t][r] = S[q=l15][k = t*16 + hi*4 + r]
        f32x4 s[4];
        {
            f32x4 z = {0.f, 0.f, 0.f, 0.f};
            s[0] = __builtin_amdgcn_mfma_f32_16x16x32_bf16(kc0, qf, z, 0, 0, 0);
            s[1] = __builtin_amdgcn_mfma_f32_16x16x32_bf16(kc1, qf, z, 0, 0, 0);
            s[2] = __builtin_amdgcn_mfma_f32_16x16x32_bf16(kc2, qf, z, 0, 0, 0);
            s[3] = __builtin_amdgcn_mfma_f32_16x16x32_bf16(kc3, qf, z, 0, 0, 0);
        }
        if (kb == WN) {
            #pragma unroll
            for (int t = 0; t < 4; t++)
                #pragma unroll
                for (int r = 0; r < 4; r++)
                    if (t * 16 + hi * 4 + r >= NQtok) s[t][r] = -1e30f;
        }

        // prefetch next window's K AND V fragments (one full window ahead)
        int nkb = -1;
        bf16x8 kn0, kn1, kn2, kn3, vn0, vn1, vn2, vn3;
        if (bits) {
            nkb = __builtin_ctzll(bits);
            bits &= bits - 1;
            long nbase = ((long)bh * SP + nkb * 64) * HD;
            const short* Kn = Kbf + nbase + hi * 8;
            kn0 = *(const bf16x8*)(Kn + (0 * 16 + l15) * HD);
            kn1 = *(const bf16x8*)(Kn + (1 * 16 + l15) * HD);
            kn2 = *(const bf16x8*)(Kn + (2 * 16 + l15) * HD);
            kn3 = *(const bf16x8*)(Kn + (3 * 16 + l15) * HD);
            const short* Vn = Vtb + nbase;
            vn0 = *(const bf16x8*)&Vn[l15 * 64 + hi * 8];
            vn1 = *(const bf16x8*)&Vn[(16 + l15) * 64 + hi * 8];
            vn2 = *(const bf16x8*)&Vn[l15 * 64 + 32 + hi * 8];
            vn3 = *(const bf16x8*)&Vn[(16 + l15) * 64 + 32 + hi * 8];
        }

        // no-max softmax: logits O(1); exp safe (clamp 30); masked -> 0
        float ps = 0.f;
        #pragma unroll
        for (int t = 0; t < 4; t++) {
            #pragma unroll
            for (int r = 0; r < 4; r++) {
                float p = __expf(fminf(s[t][r], 30.f));
                s[t][r] = p;
                ps += p;
            }
        }
        l_run += ps;

        // pack P row into LDS
        #pragma unroll
        for (int t = 0; t < 4; t++) {
            uint2 pw;
            pw.x = pk2(s[t][0], s[t][1]);
            pw.y = pk2(s[t][2], s[t][3]);
            *(uint2*)&Pl[w][l15][t * 8 + hi * 2] = pw;
        }
        bf16x8 pb0 = *(const bf16x8*)&Pl[w][l15][hi * 4];
        bf16x8 pb1 = *(const bf16x8*)&Pl[w][l15][16 + hi * 4];

        // PV swapped: acc[d][q] += V^T[d][k] * P[q][k]
        acc0 = __builtin_amdgcn_mfma_f32_16x16x32_bf16(va, pb0, acc0, 0, 0, 0);
        acc1 = __builtin_amdgcn_mfma_f32_16x16x32_bf16(vb, pb0, acc1, 0, 0, 0);
        acc0 = __builtin_amdgcn_mfma_f32_16x16x32_bf16(vc, pb1, acc0, 0, 0, 0);
        acc1 = __builtin_amdgcn_mfma_f32_16x16x32_bf16(vd, pb1, acc1, 0, 0, 0);

        if (nkb < 0) break;
        kb = nkb;
        kc0 = kn0; kc1 = kn1; kc2 = kn2; kc3 = kn3;
        va = vn0; vb = vn1; vc = vn2; vd = vn3;
    }

    float lsum = l_run;
    lsum += __shfl_xor(lsum, 16);
    lsum += __shfl_xor(lsum, 32);

    if (!is_cls) {
        float inv = 1.f / lsum;
        int wh = (qb / 7) * 8, wwc = (qb % 7) * 8;
        int inner = w * 16 + l15;
        int h0 = wh + (inner >> 3), w0 = wwc + (inner & 7);
        int c0 = head * HD + hi * 4;
        float u0[4], u1[4];
        #pragma unroll
        for (int r = 0; r < 4; r++) {
            u0[r] = acc0[r] * inv + lepe_b[c0 + r];
            u1[r] = acc1[r] * inv + lepe_b[c0 + 16 + r];
        }
        #pragma unroll
        for (int dh = -1; dh <= 1; dh++) {
            int h2 = h0 + dh;
            if (h2 < 0 || h2 >= Himg) continue;
            #pragma unroll
            for (int dw = -1; dw <= 1; dw++) {
                int w2 = w0 + dw;
                if (w2 < 0 || w2 >= Wimg) continue;
                long vbase = ((long)b * SIMG + h2 * Wimg + w2) * CC;
                int j = (dh + 1) * 3 + (dw + 1);
                ushort4 v0 = *(const ushort4*)&Vsp[vbase + c0];
                ushort4 v1 = *(const ushort4*)&Vsp[vbase + c0 + 16];
                float4 g0 = *(const float4*)&lepe_w[j * CC + c0];
                float4 g1 = *(const float4*)&lepe_w[j * CC + c0 + 16];
                u0[0] += bf2f(v0.x) * g0.x; u0[1] += bf2f(v0.y) * g0.y;
                u0[2] += bf2f(v0.z) * g0.z; u0[3] += bf2f(v0.w) * g0.w;
                u1[0] += bf2f(v1.x) * g1.x; u1[1] += bf2f(v1.y) * g1.y;
                u1[2] += bf2f(v1.z) * g1.z; u1[3] += bf2f(v1.w) * g1.w;
            }
        }
        long ubase = ((long)(b * SS + h0 * Wimg + w0)) * CC + c0;
        ushort4 o0, o1;
        o0.x = (unsigned short)f2bf(u0[0]); o0.y = (unsigned short)f2bf(u0[1]);
        o0.z = (unsigned short)f2bf(u0[2]); o0.w = (unsigned short)f2bf(u0[3]);
        o1.x = (unsigned short)f2bf(u1[0]); o1.y = (unsigned short)f2bf(u1[1]);
        o1.z = (unsigned short)f2bf(u1[2]); o1.w = (unsigned short)f2bf(u1[3]);
        *(ushort4*)&U[ubase]      = o0;
        *(ushort4*)&U[ubase + 16] = o1;
    } else {
        if (hi == 0) Ls[w][l15] = lsum;
        #pragma unroll
        for (int r = 0; r < 4; r++) {
            MAcc[w][l15][hi * 4 + r]      = acc0[r];
            MAcc[w][l15][16 + hi * 4 + r] = acc1[r];
        }
        __syncthreads();
        if (w == 0) {
            float L = Ls[0][l15] + Ls[1][l15] + Ls[2][l15] + Ls[3][l15];
            float o0[4] = {0.f, 0.f, 0.f, 0.f}, o1[4] = {0.f, 0.f, 0.f, 0.f};
            #pragma unroll
            for (int ww = 0; ww < 4; ww++) {
                #pragma unroll
                for (int r = 0; r < 4; r++) {
                    o0[r] += MAcc[ww][l15][hi * 4 + r];
                    o1[r] += MAcc[ww][l15][16 + hi * 4 + r];
                }
            }
            if (l15 < NQtok) {
                float invL = 1.f / L;
                long ubase = ((long)(b * SS + SIMG + l15)) * CC + head * HD + hi * 4;
                ushort4 q0, q1;
                q0.x = (unsigned short)f2bf(o0[0] * invL);
                q0.y = (unsigned short)f2bf(o0[1] * invL);
                q0.z = (unsigned short)f2bf(o0[2] * invL);
                q0.w = (unsigned short)f2bf(o0[3] * invL);
                q1.x = (unsigned short)f2bf(o1[0] * invL);
                q1.y = (unsigned short)f2bf(o1[1] * invL);
                q1.z = (unsigned short)f2bf(o1[2] * invL);
                q1.w = (unsigned short)f2bf(o1[3] * invL);
                *(ushort4*)&U[ubase]      = q0;
                *(ushort4*)&U[ubase + 16] = q1;
            }
        }
    }
}

// ---------------------------------------------------------------- out GEMM (MFMA)
// 128-row blocks, B-fragments direct from pre-transposed bf16 Wot (global/L2).
__global__ __launch_bounds__(256, 2) void out_gemm_mfma(
        const short* __restrict__ U, const short* __restrict__ Wot,
        const float* __restrict__ bo, float* __restrict__ out) {
    int tid = threadIdx.x;
    int w = tid >> 6, l = tid & 63, l15 = l & 15, hi = l >> 4;
    int row0 = blockIdx.x * 128 + w * 32;
    int n0 = blockIdx.y * 64;
    f32x4 acc[2][4];
    #pragma unroll
    for (int rs = 0; rs < 2; rs++)
        #pragma unroll
        for (int t = 0; t < 4; t++) acc[rs][t] = (f32x4){0.f, 0.f, 0.f, 0.f};
    const short* Ap0 = U + (long)(row0 + l15) * CC + hi * 8;
    const short* Ap1 = Ap0 + 16 * CC;
    const short* Bp = Wot + (long)(n0 + l15) * CC + hi * 8;
    #pragma unroll
    for (int k0 = 0; k0 < 256; k0 += 32) {
        bf16x8 a0 = *(const bf16x8*)(Ap0 + k0);
        bf16x8 a1 = *(const bf16x8*)(Ap1 + k0);
        #pragma unroll
        for (int t = 0; t < 4; t++) {
            bf16x8 bf = *(const bf16x8*)(Bp + t * 16 * CC + k0);
            acc[0][t] = __builtin_amdgcn_mfma_f32_16x16x32_bf16(a0, bf, acc[0][t], 0, 0, 0);
            acc[1][t] = __builtin_amdgcn_mfma_f32_16x16x32_bf16(a1, bf, acc[1][t], 0, 0, 0);
        }
    }
    float bias[4];
    #pragma unroll
    for (int t = 0; t < 4; t++) bias[t] = bo[n0 + t * 16 + l15];
    #pragma unroll
    for (int rs = 0; rs < 2; rs++) {
        #pragma unroll
        for (int r = 0; r < 4; r++) {
            int row = row0 + rs * 16 + hi * 4 + r;
            if (row >= NROWS) continue;
            int b = (row >= SS) ? 1 : 0;
            int tok = row - b * SS;
            long base;
            if (tok < SIMG) base = (long)(b * SIMG + tok) * CC;
            else base = (long)Bsz * SIMG * CC + (long)(b * NQtok + tok - SIMG) * CC;
            #pragma unroll
            for (int t = 0; t < 4; t++)
                out[base + n0 + t * 16 + l15] = acc[rs][t][r] + bias[t];
        }
    }
}

// ---------------------------------------------------------------- launch
extern "C" void kernel_launch(void* const* d_in, const int* in_sizes, int n_in,
                              void* d_out, int out_size, void* d_ws, size_t ws_size,
                              hipStream_t stream) {
    const float* x      = (const float*)d_in[0];
    const float* cls    = (const float*)d_in[1];
    const unsigned char* mask_raw = (const unsigned char*)d_in[2];
    const float* Wqkv   = (const float*)d_in[3];
    const float* bqkv   = (const float*)d_in[4];
    const float* lepe_w = (const float*)d_in[5];
    const float* lepe_b = (const float*)d_in[6];
    const float* Wo     = (const float*)d_in[7];
    const float* bo     = (const float*)d_in[8];
    float* out = (float*)d_out;

    short* Qbf = (short*)d_ws;
    short* Kbf = Qbf + QSZ;
    short* Vtb = Kbf + QSZ;
    short* U   = Vtb + QSZ;
    short* Vsp = U + USZ;
    short* Wot = Vsp + VSPSZ;

    qkv_fused<<<dim3(MROWS / 64, 12), 256, 0, stream>>>(
        x, cls, Wqkv, bqkv, Wo, Qbf, Kbf, Vtb, Vsp, Wot);
    attn_mfma<<<Bsz * NHd * NWIN, 256, 0, stream>>>(
        Qbf, Kbf, Vtb, Vsp, lepe_w, lepe_b, mask_raw, U);
    out_gemm_mfma<<<dim3(MROWS / 128, 4), 256, 0, stream>>>(U, Wot, bo, out);
}

// Round 18
// 72.057 us; speedup vs baseline: 1.0039x; 1.0039x over previous
//
#include <hip/hip_runtime.h>
#include <hip/hip_bf16.h>
#include <math.h>

#define Bsz 2
#define NHd 8
#define HD 32
#define CC 256
#define Himg 56
#define Wimg 56
#define SIMG 3136
#define NQtok 15
#define SS 3151           // SIMG + NQtok
#define SP 3200           // padded to 50*64
#define NWIN 50           // 49 image windows + 1 cls block
#define WN 49
#define MM 50             // mask dim
#define MROWS (Bsz*SP)    // 6400 padded token rows
#define NROWS (Bsz*SS)    // 6302 real rows

#define QSZ (Bsz*NHd*SP*HD)     // 1,638,400 elements per tensor
#define VSPSZ (Bsz*SIMG*CC)     // 1,605,632 (bf16)
#define USZ (MROWS*CC)          // 1,638,400 (bf16 U, padded rows)

typedef __attribute__((ext_vector_type(8))) short bf16x8;
typedef __attribute__((ext_vector_type(4))) float f32x4;

__device__ __forceinline__ short f2bf(float f) {
    __hip_bfloat16 h = __float2bfloat16(f);
    return *reinterpret_cast<short*>(&h);
}
__device__ __forceinline__ float bf2f(unsigned short s) {
    unsigned int u = ((unsigned int)s) << 16;
    return __uint_as_float(u);
}
__device__ __forceinline__ unsigned int pk2(float lo, float hi) {
    return ((unsigned int)(unsigned short)f2bf(hi) << 16)
         | (unsigned int)(unsigned short)f2bf(lo);
}
__device__ __forceinline__ bf16x8 cvt8(const float* p) {
    float4 a = *(const float4*)p, b = *(const float4*)(p + 4);
    bf16x8 o;
    o[0] = f2bf(a.x); o[1] = f2bf(a.y); o[2] = f2bf(a.z); o[3] = f2bf(a.w);
    o[4] = f2bf(b.x); o[5] = f2bf(b.y); o[6] = f2bf(b.z); o[7] = f2bf(b.w);
    return o;
}

// Stage a 64-col x 256-k column block of W (row-major [K][ld]) transposed
// into LDS Wl[n][k] as bf16. Coalesced: lane = n, 8 k-rows per ds_write_b128.
__device__ __forceinline__ void stage_wt(const float* __restrict__ W, int ld,
                                         int n0, int tid, short (*Wl)[264]) {
    int n = tid & 63;
    #pragma unroll
    for (int i = 0; i < 8; i++) {
        int k0 = ((tid >> 6) + i * 4) * 8;
        bf16x8 o;
        #pragma unroll
        for (int j = 0; j < 8; j++) o[j] = f2bf(W[(long)(k0 + j) * ld + n0 + n]);
        *(bf16x8*)&Wl[n][k0] = o;
    }
}

// ---------------------------------------------------------------- QKV GEMM (fused prep)
// Grid (100 rowblocks x 6 col-pairs). Block stages its A-tile ONCE (f32->bf16),
// then serves two 64-col W^T tiles sequentially (Wl re-staged between phases).
// Halves A-stage traffic/cvt vs (100,12); same W traffic and MFMA count.
__global__ __launch_bounds__(256, 2) void qkv_fused(
        const float* __restrict__ x, const float* __restrict__ cls,
        const float* __restrict__ Wqkv, const float* __restrict__ bqkv,
        short* __restrict__ Qbf, short* __restrict__ Kbf, short* __restrict__ Vtb,
        short* __restrict__ Vsp) {
    __shared__ __align__(16) short As[64][264];
    __shared__ __align__(16) short Wl[64][264];
    int tid = threadIdx.x;
    int w = tid >> 6, l = tid & 63, l15 = l & 15, hi = l >> 4;
    int rb = blockIdx.x, nb = blockIdx.y;      // nb in [0,6): 128-col pair

    // stage A (64 rows x 256 cols, f32 -> bf16) — once per block
    #pragma unroll
    for (int p = 0; p < 8; p++) {
        int r = p * 8 + (tid >> 5);
        int c8 = (tid & 31) * 8;
        int row = rb * 64 + r;
        int b = row / SP, tok = row % SP;
        bf16x8 o = {0, 0, 0, 0, 0, 0, 0, 0};
        const float* pp = nullptr;
        if (tok < SIMG)      pp = x + (long)(b * SIMG + tok) * CC + c8;
        else if (tok < SS)   pp = cls + (long)(b * NQtok + tok - SIMG) * CC + c8;
        if (pp) o = cvt8(pp);
        *(bf16x8*)&As[r][c8] = o;
    }

    f32x4 acc[2][4];
    #pragma unroll
    for (int cc2 = 0; cc2 < 2; cc2++)
        #pragma unroll
        for (int t = 0; t < 4; t++) acc[cc2][t] = (f32x4){0.f, 0.f, 0.f, 0.f};

    for (int cc2 = 0; cc2 < 2; cc2++) {
        int n0 = nb * 128 + cc2 * 64;
        __syncthreads();               // As visible (iter 0) / Wl reads done (iter 1)
        stage_wt(Wqkv, 768, n0, tid, Wl);
        __syncthreads();
        #pragma unroll
        for (int k0 = 0; k0 < 256; k0 += 32) {
            bf16x8 a = *(const bf16x8*)&As[w * 16 + l15][k0 + hi * 8];
            #pragma unroll
            for (int t = 0; t < 4; t++) {
                bf16x8 bf = *(const bf16x8*)&Wl[t * 16 + l15][k0 + hi * 8];
                acc[cc2][t] = __builtin_amdgcn_mfma_f32_16x16x32_bf16(a, bf, acc[cc2][t], 0, 0, 0);
            }
        }
    }

    float bias[2][4];
    #pragma unroll
    for (int cc2 = 0; cc2 < 2; cc2++)
        #pragma unroll
        for (int t = 0; t < 4; t++) bias[cc2][t] = bqkv[nb * 128 + cc2 * 64 + t * 16 + l15];
    int which = nb >> 1;                  // 0=Q 1=K 2=V (128-col pair within one output)
    #pragma unroll
    for (int r = 0; r < 4; r++) {
        int row = rb * 64 + w * 16 + hi * 4 + r;
        int b = row / SP, tok = row % SP;
        int s;
        if (tok < SIMG) {
            int h = tok / Wimg, wq = tok % Wimg;
            s = (((h >> 3) * 7 + (wq >> 3)) << 6) | ((h & 7) << 3) | (wq & 7);
        } else s = tok;
        #pragma unroll
        for (int cc2 = 0; cc2 < 2; cc2++) {
            #pragma unroll
            for (int t = 0; t < 4; t++) {
                int n = nb * 128 + cc2 * 64 + t * 16 + l15;
                float v = acc[cc2][t][r] + bias[cc2][t];
                int cch = n & 255;
                int head = cch >> 5, d = cch & 31;
                long off = (((long)(b * NHd + head)) * SP + s) * HD + d;
                if (which == 0)      Qbf[off] = f2bf(v * 0.0625f);   // scale = 256^-0.5
                else if (which == 1) Kbf[off] = f2bf(v);
                else {
                    short vb = f2bf(v);
                    Vtb[(((long)(b * NHd + head)) * NWIN + (s >> 6)) * 2048
                        + d * 64 + (s & 63)] = vb;
                    if (tok < SIMG) Vsp[(long)(b * SIMG + tok) * CC + cch] = vb;
                }
            }
        }
    }
}

// ---------------------------------------------------------------- attention + LEPE
// Round-13 structure: block = (bh, qwin), 4 barrier-free waves; K prefetch one
// window ahead; swapped-operand QK^T + no-max flash; fused LEPE epilogue;
// bf16 U output. s_setprio(1) wraps the MFMA clusters (T5: independent waves).
__global__ __launch_bounds__(256, 2) void attn_mfma(
        const short* __restrict__ Qbf, const short* __restrict__ Kbf,
        const short* __restrict__ Vtb, const short* __restrict__ Vsp,
        const float* __restrict__ lepe_w, const float* __restrict__ lepe_b,
        const unsigned char* __restrict__ raw,
        short* __restrict__ U) {
    __shared__ __align__(16) unsigned int Pl[4][16][36];
    __shared__ float Ls[4][16];
    __shared__ float MAcc[4][16][32];

    int qb = blockIdx.x % NWIN;
    int bh = blockIdx.x / NWIN;
    int b = bh >> 3, head = bh & 7;
    int tid = threadIdx.x;
    int w = tid >> 6;
    int l = tid & 63;
    int l15 = l & 15;
    int hi = l >> 4;
    bool is_cls = (qb == WN);
    int qrow0 = is_cls ? 0 : w * 16;

    bf16x8 qf = *(const bf16x8*)&Qbf[((long)bh * SP + qb * 64 + qrow0 + l15) * HD + hi * 8];

    f32x4 acc0 = {0.f, 0.f, 0.f, 0.f};   // O[d=hi*4+reg][q=l15]
    f32x4 acc1 = {0.f, 0.f, 0.f, 0.f};   // O[d=16+hi*4+reg][q=l15]
    float l_run = 0.f;

    unsigned long long bits;
    if (!is_cls) {
        // inline mask canonicalization: bool bytes vs 4-byte layout
        bool isbool = (raw[2453] | raw[2457] | raw[2461]) != 0;
        bool mv = false;
        long e = (long)b * MM * MM + (long)qb * MM + l;
        if (isbool) {
            if (l < NWIN) mv = raw[e] != 0;
        } else {
            if (l < NWIN) mv = ((const unsigned int*)raw)[e] != 0;
        }
        bits = __ballot(l < NWIN && mv);
    } else {
        bits = (0x1111111111111ULL << w) & ((1ULL << 50) - 1);
    }

    int kb = __builtin_ctzll(bits);
    bits &= bits - 1;
    const short* Kp = Kbf + ((long)bh * SP + kb * 64) * HD + hi * 8;
    bf16x8 kc0 = *(const bf16x8*)(Kp + (0 * 16 + l15) * HD);
    bf16x8 kc1 = *(const bf16x8*)(Kp + (1 * 16 + l15) * HD);
    bf16x8 kc2 = *(const bf16x8*)(Kp + (2 * 16 + l15) * HD);
    bf16x8 kc3 = *(const bf16x8*)(Kp + (3 * 16 + l15) * HD);

    for (;;) {
        long kbase = ((long)bh * SP + kb * 64) * HD;
        const short* Vp = Vtb + kbase;
        bf16x8 va = *(const bf16x8*)&Vp[l15 * 64 + hi * 8];
        bf16x8 vb = *(const bf16x8*)&Vp[(16 + l15) * 64 + hi * 8];
        bf16x8 vc = *(const bf16x8*)&Vp[l15 * 64 + 32 + hi * 8];
        bf16x8 vd = *(const bf16x8*)&Vp[(16 + l15) * 64 + 32 + hi * 8];

        // QK^T swapped: s[t][r] = S[q=l15][k = t*16 + hi*4 + r]
        f32x4 s[4];
        {
            f32x4 z = {0.f, 0.f, 0.f, 0.f};
            __builtin_amdgcn_s_setprio(1);
            s[0] = __builtin_amdgcn_mfma_f32_16x16x32_bf16(kc0, qf, z, 0, 0, 0);
            s[1] = __builtin_amdgcn_mfma_f32_16x16x32_bf16(kc1, qf, z, 0, 0, 0);
            s[2] = __builtin_amdgcn_mfma_f32_16x16x32_bf16(kc2, qf, z, 0, 0, 0);
            s[3] = __builtin_amdgcn_mfma_f32_16x16x32_bf16(kc3, qf, z, 0, 0, 0);
            __builtin_amdgcn_s_setprio(0);
        }
        if (kb == WN) {
            #pragma unroll
            for (int t = 0; t < 4; t++)
                #pragma unroll
                for (int r = 0; r < 4; r++)
                    if (t * 16 + hi * 4 + r >= NQtok) s[t][r] = -1e30f;
        }

        // prefetch next window's K fragments
        int nkb = -1;
        bf16x8 kn0, kn1, kn2, kn3;
        if (bits) {
            nkb = __builtin_ctzll(bits);
            bits &= bits - 1;
            const short* Kn = Kbf + ((long)bh * SP + nkb * 64) * HD + hi * 8;
            kn0 = *(const bf16x8*)(Kn + (0 * 16 + l15) * HD);
            kn1 = *(const bf16x8*)(Kn + (1 * 16 + l15) * HD);
            kn2 = *(const bf16x8*)(Kn + (2 * 16 + l15) * HD);
            kn3 = *(const bf16x8*)(Kn + (3 * 16 + l15) * HD);
        }

        // no-max softmax: logits O(1); exp safe (clamp 30); masked -> 0
        float ps = 0.f;
        #pragma unroll
        for (int t = 0; t < 4; t++) {
            #pragma unroll
            for (int r = 0; r < 4; r++) {
                float p = __expf(fminf(s[t][r], 30.f));
                s[t][r] = p;
                ps += p;
            }
        }
        l_run += ps;

        // pack P row into LDS
        #pragma unroll
        for (int t = 0; t < 4; t++) {
            uint2 pw;
            pw.x = pk2(s[t][0], s[t][1]);
            pw.y = pk2(s[t][2], s[t][3]);
            *(uint2*)&Pl[w][l15][t * 8 + hi * 2] = pw;
        }
        bf16x8 pb0 = *(const bf16x8*)&Pl[w][l15][hi * 4];
        bf16x8 pb1 = *(const bf16x8*)&Pl[w][l15][16 + hi * 4];

        // PV swapped: acc[d][q] += V^T[d][k] * P[q][k]
        __builtin_amdgcn_s_setprio(1);
        acc0 = __builtin_amdgcn_mfma_f32_16x16x32_bf16(va, pb0, acc0, 0, 0, 0);
        acc1 = __builtin_amdgcn_mfma_f32_16x16x32_bf16(vb, pb0, acc1, 0, 0, 0);
        acc0 = __builtin_amdgcn_mfma_f32_16x16x32_bf16(vc, pb1, acc0, 0, 0, 0);
        acc1 = __builtin_amdgcn_mfma_f32_16x16x32_bf16(vd, pb1, acc1, 0, 0, 0);
        __builtin_amdgcn_s_setprio(0);

        if (nkb < 0) break;
        kb = nkb;
        kc0 = kn0; kc1 = kn1; kc2 = kn2; kc3 = kn3;
    }

    float lsum = l_run;
    lsum += __shfl_xor(lsum, 16);
    lsum += __shfl_xor(lsum, 32);

    if (!is_cls) {
        float inv = 1.f / lsum;
        int wh = (qb / 7) * 8, wwc = (qb % 7) * 8;
        int inner = w * 16 + l15;
        int h0 = wh + (inner >> 3), w0 = wwc + (inner & 7);
        int c0 = head * HD + hi * 4;
        float u0[4], u1[4];
        #pragma unroll
        for (int r = 0; r < 4; r++) {
            u0[r] = acc0[r] * inv + lepe_b[c0 + r];
            u1[r] = acc1[r] * inv + lepe_b[c0 + 16 + r];
        }
        #pragma unroll
        for (int dh = -1; dh <= 1; dh++) {
            int h2 = h0 + dh;
            if (h2 < 0 || h2 >= Himg) continue;
            #pragma unroll
            for (int dw = -1; dw <= 1; dw++) {
                int w2 = w0 + dw;
                if (w2 < 0 || w2 >= Wimg) continue;
                long vbase = ((long)b * SIMG + h2 * Wimg + w2) * CC;
                int j = (dh + 1) * 3 + (dw + 1);
                ushort4 v0 = *(const ushort4*)&Vsp[vbase + c0];
                ushort4 v1 = *(const ushort4*)&Vsp[vbase + c0 + 16];
                float4 g0 = *(const float4*)&lepe_w[j * CC + c0];
                float4 g1 = *(const float4*)&lepe_w[j * CC + c0 + 16];
                u0[0] += bf2f(v0.x) * g0.x; u0[1] += bf2f(v0.y) * g0.y;
                u0[2] += bf2f(v0.z) * g0.z; u0[3] += bf2f(v0.w) * g0.w;
                u1[0] += bf2f(v1.x) * g1.x; u1[1] += bf2f(v1.y) * g1.y;
                u1[2] += bf2f(v1.z) * g1.z; u1[3] += bf2f(v1.w) * g1.w;
            }
        }
        long ubase = ((long)(b * SS + h0 * Wimg + w0)) * CC + c0;
        ushort4 o0, o1;
        o0.x = (unsigned short)f2bf(u0[0]); o0.y = (unsigned short)f2bf(u0[1]);
        o0.z = (unsigned short)f2bf(u0[2]); o0.w = (unsigned short)f2bf(u0[3]);
        o1.x = (unsigned short)f2bf(u1[0]); o1.y = (unsigned short)f2bf(u1[1]);
        o1.z = (unsigned short)f2bf(u1[2]); o1.w = (unsigned short)f2bf(u1[3]);
        *(ushort4*)&U[ubase]      = o0;
        *(ushort4*)&U[ubase + 16] = o1;
    } else {
        if (hi == 0) Ls[w][l15] = lsum;
        #pragma unroll
        for (int r = 0; r < 4; r++) {
            MAcc[w][l15][hi * 4 + r]      = acc0[r];
            MAcc[w][l15][16 + hi * 4 + r] = acc1[r];
        }
        __syncthreads();
        if (w == 0) {
            float L = Ls[0][l15] + Ls[1][l15] + Ls[2][l15] + Ls[3][l15];
            float o0[4] = {0.f, 0.f, 0.f, 0.f}, o1[4] = {0.f, 0.f, 0.f, 0.f};
            #pragma unroll
            for (int ww = 0; ww < 4; ww++) {
                #pragma unroll
                for (int r = 0; r < 4; r++) {
                    o0[r] += MAcc[ww][l15][hi * 4 + r];
                    o1[r] += MAcc[ww][l15][16 + hi * 4 + r];
                }
            }
            if (l15 < NQtok) {
                float invL = 1.f / L;
                long ubase = ((long)(b * SS + SIMG + l15)) * CC + head * HD + hi * 4;
                ushort4 q0, q1;
                q0.x = (unsigned short)f2bf(o0[0] * invL);
                q0.y = (unsigned short)f2bf(o0[1] * invL);
                q0.z = (unsigned short)f2bf(o0[2] * invL);
                q0.w = (unsigned short)f2bf(o0[3] * invL);
                q1.x = (unsigned short)f2bf(o1[0] * invL);
                q1.y = (unsigned short)f2bf(o1[1] * invL);
                q1.z = (unsigned short)f2bf(o1[2] * invL);
                q1.w = (unsigned short)f2bf(o1[3] * invL);
                *(ushort4*)&U[ubase]      = q0;
                *(ushort4*)&U[ubase + 16] = q1;
            }
        }
    }
}

// ---------------------------------------------------------------- out GEMM (fused Wo prep)
// 128-row blocks; block stages its Wo^T column tile into LDS; U read direct.
__global__ __launch_bounds__(256, 2) void out_fused(
        const short* __restrict__ U, const float* __restrict__ Wo,
        const float* __restrict__ bo, float* __restrict__ out) {
    __shared__ __align__(16) short Wl[64][264];
    int tid = threadIdx.x;
    int w = tid >> 6, l = tid & 63, l15 = l & 15, hi = l >> 4;
    int row0 = blockIdx.x * 128 + w * 32;
    int n0 = blockIdx.y * 64;

    stage_wt(Wo, 256, n0, tid, Wl);
    __syncthreads();

    f32x4 acc[2][4];
    #pragma unroll
    for (int rs = 0; rs < 2; rs++)
        #pragma unroll
        for (int t = 0; t < 4; t++) acc[rs][t] = (f32x4){0.f, 0.f, 0.f, 0.f};
    const short* Ap0 = U + (long)(row0 + l15) * CC + hi * 8;
    const short* Ap1 = Ap0 + 16 * CC;
    #pragma unroll
    for (int k0 = 0; k0 < 256; k0 += 32) {
        bf16x8 a0 = *(const bf16x8*)(Ap0 + k0);
        bf16x8 a1 = *(const bf16x8*)(Ap1 + k0);
        #pragma unroll
        for (int t = 0; t < 4; t++) {
            bf16x8 bf = *(const bf16x8*)&Wl[t * 16 + l15][k0 + hi * 8];
            acc[0][t] = __builtin_amdgcn_mfma_f32_16x16x32_bf16(a0, bf, acc[0][t], 0, 0, 0);
            acc[1][t] = __builtin_amdgcn_mfma_f32_16x16x32_bf16(a1, bf, acc[1][t], 0, 0, 0);
        }
    }
    float bias[4];
    #pragma unroll
    for (int t = 0; t < 4; t++) bias[t] = bo[n0 + t * 16 + l15];
    #pragma unroll
    for (int rs = 0; rs < 2; rs++) {
        #pragma unroll
        for (int r = 0; r < 4; r++) {
            int row = row0 + rs * 16 + hi * 4 + r;
            if (row >= NROWS) continue;
            int b = (row >= SS) ? 1 : 0;
            int tok = row - b * SS;
            long base;
            if (tok < SIMG) base = (long)(b * SIMG + tok) * CC;
            else base = (long)Bsz * SIMG * CC + (long)(b * NQtok + tok - SIMG) * CC;
            #pragma unroll
            for (int t = 0; t < 4; t++)
                out[base + n0 + t * 16 + l15] = acc[rs][t][r] + bias[t];
        }
    }
}

// ---------------------------------------------------------------- launch
extern "C" void kernel_launch(void* const* d_in, const int* in_sizes, int n_in,
                              void* d_out, int out_size, void* d_ws, size_t ws_size,
                              hipStream_t stream) {
    const float* x      = (const float*)d_in[0];
    const float* cls    = (const float*)d_in[1];
    const unsigned char* mask_raw = (const unsigned char*)d_in[2];
    const float* Wqkv   = (const float*)d_in[3];
    const float* bqkv   = (const float*)d_in[4];
    const float* lepe_w = (const float*)d_in[5];
    const float* lepe_b = (const float*)d_in[6];
    const float* Wo     = (const float*)d_in[7];
    const float* bo     = (const float*)d_in[8];
    float* out = (float*)d_out;

    short* Qbf = (short*)d_ws;
    short* Kbf = Qbf + QSZ;
    short* Vtb = Kbf + QSZ;
    short* U   = Vtb + QSZ;
    short* Vsp = U + USZ;

    qkv_fused<<<dim3(MROWS / 64, 6), 256, 0, stream>>>(
        x, cls, Wqkv, bqkv, Qbf, Kbf, Vtb, Vsp);
    attn_mfma<<<Bsz * NHd * NWIN, 256, 0, stream>>>(
        Qbf, Kbf, Vtb, Vsp, lepe_w, lepe_b, mask_raw, U);
    out_fused<<<dim3(MROWS / 128, 4), 256, 0, stream>>>(U, Wo, bo, out);
}

// Round 19
// 69.403 us; speedup vs baseline: 1.0423x; 1.0382x over previous
//
#include <hip/hip_runtime.h>
#include <hip/hip_bf16.h>
#include <math.h>

#define Bsz 2
#define NHd 8
#define HD 32
#define CC 256
#define Himg 56
#define Wimg 56
#define SIMG 3136
#define NQtok 15
#define SS 3151           // SIMG + NQtok
#define SP 3200           // padded to 50*64
#define NWIN 50           // 49 image windows + 1 cls block
#define WN 49
#define MM 50             // mask dim
#define MROWS (Bsz*SP)    // 6400 padded token rows
#define NROWS (Bsz*SS)    // 6302 real rows

#define QSZ (Bsz*NHd*SP*HD)     // 1,638,400 elements per tensor
#define VSPSZ (Bsz*SIMG*CC)     // 1,605,632 (bf16)
#define USZ (MROWS*CC)          // 1,638,400 (bf16 U, padded rows)

typedef __attribute__((ext_vector_type(8))) short bf16x8;
typedef __attribute__((ext_vector_type(4))) float f32x4;

__device__ __forceinline__ short f2bf(float f) {
    __hip_bfloat16 h = __float2bfloat16(f);
    return *reinterpret_cast<short*>(&h);
}
__device__ __forceinline__ float bf2f(unsigned short s) {
    unsigned int u = ((unsigned int)s) << 16;
    return __uint_as_float(u);
}
__device__ __forceinline__ unsigned int pk2(float lo, float hi) {
    return ((unsigned int)(unsigned short)f2bf(hi) << 16)
         | (unsigned int)(unsigned short)f2bf(lo);
}
__device__ __forceinline__ bf16x8 cvt8(const float* p) {
    float4 a = *(const float4*)p, b = *(const float4*)(p + 4);
    bf16x8 o;
    o[0] = f2bf(a.x); o[1] = f2bf(a.y); o[2] = f2bf(a.z); o[3] = f2bf(a.w);
    o[4] = f2bf(b.x); o[5] = f2bf(b.y); o[6] = f2bf(b.z); o[7] = f2bf(b.w);
    return o;
}

// Stage a 64-col x 256-k column block of W (row-major [K][ld]) transposed
// into LDS Wl[n][k] as bf16. Per pass: lane = n (coalesced across wave),
// 8 consecutive k rows -> one ds_write_b128.
__device__ __forceinline__ void stage_wt(const float* __restrict__ W, int ld,
                                         int n0, int tid, short (*Wl)[264]) {
    int n = tid & 63;
    #pragma unroll
    for (int i = 0; i < 8; i++) {
        int k0 = ((tid >> 6) + i * 4) * 8;
        bf16x8 o;
        #pragma unroll
        for (int j = 0; j < 8; j++) o[j] = f2bf(W[(long)(k0 + j) * ld + n0 + n]);
        *(bf16x8*)&Wl[n][k0] = o;
    }
}

// ---------------------------------------------------------------- QKV GEMM (fused prep)
// Grid (100 rowblocks x 12 colblocks). Block stages its A-tile (f32->bf16) and
// its W^T column tile into LDS, then 8 k-steps x 4 MFMA per wave.
__global__ __launch_bounds__(256, 2) void qkv_fused(
        const float* __restrict__ x, const float* __restrict__ cls,
        const float* __restrict__ Wqkv, const float* __restrict__ bqkv,
        short* __restrict__ Qbf, short* __restrict__ Kbf, short* __restrict__ Vtb,
        short* __restrict__ Vsp) {
    __shared__ __align__(16) short As[64][264];
    __shared__ __align__(16) short Wl[64][264];
    int tid = threadIdx.x;
    int w = tid >> 6, l = tid & 63, l15 = l & 15, hi = l >> 4;
    int rb = blockIdx.x, nb = blockIdx.y;
    int n0 = nb * 64;

    // stage A (64 rows x 256 cols, f32 -> bf16)
    #pragma unroll
    for (int p = 0; p < 8; p++) {
        int r = p * 8 + (tid >> 5);
        int c8 = (tid & 31) * 8;
        int row = rb * 64 + r;
        int b = row / SP, tok = row % SP;
        bf16x8 o = {0, 0, 0, 0, 0, 0, 0, 0};
        const float* pp = nullptr;
        if (tok < SIMG)      pp = x + (long)(b * SIMG + tok) * CC + c8;
        else if (tok < SS)   pp = cls + (long)(b * NQtok + tok - SIMG) * CC + c8;
        if (pp) o = cvt8(pp);
        *(bf16x8*)&As[r][c8] = o;
    }
    // stage W^T column tile
    stage_wt(Wqkv, 768, n0, tid, Wl);
    __syncthreads();

    f32x4 acc[4];
    #pragma unroll
    for (int t = 0; t < 4; t++) acc[t] = (f32x4){0.f, 0.f, 0.f, 0.f};
    #pragma unroll
    for (int k0 = 0; k0 < 256; k0 += 32) {
        bf16x8 a = *(const bf16x8*)&As[w * 16 + l15][k0 + hi * 8];
        #pragma unroll
        for (int t = 0; t < 4; t++) {
            bf16x8 bf = *(const bf16x8*)&Wl[t * 16 + l15][k0 + hi * 8];
            acc[t] = __builtin_amdgcn_mfma_f32_16x16x32_bf16(a, bf, acc[t], 0, 0, 0);
        }
    }
    float bias[4];
    #pragma unroll
    for (int t = 0; t < 4; t++) bias[t] = bqkv[n0 + t * 16 + l15];
    int which = nb >> 2;                  // 0=Q 1=K 2=V
    #pragma unroll
    for (int r = 0; r < 4; r++) {
        int row = rb * 64 + w * 16 + hi * 4 + r;
        int b = row / SP, tok = row % SP;
        int s;
        if (tok < SIMG) {
            int h = tok / Wimg, wq = tok % Wimg;
            s = (((h >> 3) * 7 + (wq >> 3)) << 6) | ((h & 7) << 3) | (wq & 7);
        } else s = tok;
        #pragma unroll
        for (int t = 0; t < 4; t++) {
            int n = n0 + t * 16 + l15;
            float v = acc[t][r] + bias[t];
            int cch = n & 255;
            int head = cch >> 5, d = cch & 31;
            long off = (((long)(b * NHd + head)) * SP + s) * HD + d;
            if (which == 0)      Qbf[off] = f2bf(v * 0.0625f);   // scale = 256^-0.5
            else if (which == 1) Kbf[off] = f2bf(v);
            else {
                short vb = f2bf(v);
                Vtb[(((long)(b * NHd + head)) * NWIN + (s >> 6)) * 2048
                    + d * 64 + (s & 63)] = vb;
                if (tok < SIMG) Vsp[(long)(b * SIMG + tok) * CC + cch] = vb;
            }
        }
    }
}

// ---------------------------------------------------------------- attention + LEPE
// Swapped-operand QK^T + no-max flash (round-11 core). Mask row canonicalized
// inline per block (uniform type-detect branch) — no prep pass.
__global__ __launch_bounds__(256, 2) void attn_mfma(
        const short* __restrict__ Qbf, const short* __restrict__ Kbf,
        const short* __restrict__ Vtb, const short* __restrict__ Vsp,
        const float* __restrict__ lepe_w, const float* __restrict__ lepe_b,
        const unsigned char* __restrict__ raw,
        short* __restrict__ U) {
    __shared__ __align__(16) unsigned int Pl[4][16][36];
    __shared__ float Ls[4][16];
    __shared__ float MAcc[4][16][32];

    int qb = blockIdx.x % NWIN;
    int bh = blockIdx.x / NWIN;
    int b = bh >> 3, head = bh & 7;
    int tid = threadIdx.x;
    int w = tid >> 6;
    int l = tid & 63;
    int l15 = l & 15;
    int hi = l >> 4;
    bool is_cls = (qb == WN);
    int qrow0 = is_cls ? 0 : w * 16;

    bf16x8 qf = *(const bf16x8*)&Qbf[((long)bh * SP + qb * 64 + qrow0 + l15) * HD + hi * 8];

    f32x4 acc0 = {0.f, 0.f, 0.f, 0.f};   // O[d=hi*4+reg][q=l15]
    f32x4 acc1 = {0.f, 0.f, 0.f, 0.f};   // O[d=16+hi*4+reg][q=l15]
    float l_run = 0.f;

    unsigned long long bits;
    if (!is_cls) {
        // inline mask canonicalization: bool bytes vs 4-byte (int32/f32) layout
        bool isbool = (raw[2453] | raw[2457] | raw[2461]) != 0;
        bool mv = false;
        long e = (long)b * MM * MM + (long)qb * MM + l;
        if (isbool) {
            if (l < NWIN) mv = raw[e] != 0;
        } else {
            if (l < NWIN) mv = ((const unsigned int*)raw)[e] != 0;
        }
        bits = __ballot(l < NWIN && mv);
    } else {
        bits = (0x1111111111111ULL << w) & ((1ULL << 50) - 1);
    }

    int kb = __builtin_ctzll(bits);
    bits &= bits - 1;
    const short* Kp = Kbf + ((long)bh * SP + kb * 64) * HD + hi * 8;
    bf16x8 kc0 = *(const bf16x8*)(Kp + (0 * 16 + l15) * HD);
    bf16x8 kc1 = *(const bf16x8*)(Kp + (1 * 16 + l15) * HD);
    bf16x8 kc2 = *(const bf16x8*)(Kp + (2 * 16 + l15) * HD);
    bf16x8 kc3 = *(const bf16x8*)(Kp + (3 * 16 + l15) * HD);

    for (;;) {
        long kbase = ((long)bh * SP + kb * 64) * HD;
        const short* Vp = Vtb + kbase;
        bf16x8 va = *(const bf16x8*)&Vp[l15 * 64 + hi * 8];
        bf16x8 vb = *(const bf16x8*)&Vp[(16 + l15) * 64 + hi * 8];
        bf16x8 vc = *(const bf16x8*)&Vp[l15 * 64 + 32 + hi * 8];
        bf16x8 vd = *(const bf16x8*)&Vp[(16 + l15) * 64 + 32 + hi * 8];

        // QK^T swapped: s[t][r] = S[q=l15][k = t*16 + hi*4 + r]
        f32x4 s[4];
        {
            f32x4 z = {0.f, 0.f, 0.f, 0.f};
            s[0] = __builtin_amdgcn_mfma_f32_16x16x32_bf16(kc0, qf, z, 0, 0, 0);
            s[1] = __builtin_amdgcn_mfma_f32_16x16x32_bf16(kc1, qf, z, 0, 0, 0);
            s[2] = __builtin_amdgcn_mfma_f32_16x16x32_bf16(kc2, qf, z, 0, 0, 0);
            s[3] = __builtin_amdgcn_mfma_f32_16x16x32_bf16(kc3, qf, z, 0, 0, 0);
        }
        if (kb == WN) {
            #pragma unroll
            for (int t = 0; t < 4; t++)
                #pragma unroll
                for (int r = 0; r < 4; r++)
                    if (t * 16 + hi * 4 + r >= NQtok) s[t][r] = -1e30f;
        }

        // prefetch next window's K fragments
        int nkb = -1;
        bf16x8 kn0, kn1, kn2, kn3;
        if (bits) {
            nkb = __builtin_ctzll(bits);
            bits &= bits - 1;
            const short* Kn = Kbf + ((long)bh * SP + nkb * 64) * HD + hi * 8;
            kn0 = *(const bf16x8*)(Kn + (0 * 16 + l15) * HD);
            kn1 = *(const bf16x8*)(Kn + (1 * 16 + l15) * HD);
            kn2 = *(const bf16x8*)(Kn + (2 * 16 + l15) * HD);
            kn3 = *(const bf16x8*)(Kn + (3 * 16 + l15) * HD);
        }

        // no-max softmax: logits O(1); exp safe (clamp 30); masked -> 0
        float ps = 0.f;
        #pragma unroll
        for (int t = 0; t < 4; t++) {
            #pragma unroll
            for (int r = 0; r < 4; r++) {
                float p = __expf(fminf(s[t][r], 30.f));
                s[t][r] = p;
                ps += p;
            }
        }
        l_run += ps;

        // pack P row into LDS: word kp = t*8+hi*2+w holds k-pair (2kp, 2kp+1)
        #pragma unroll
        for (int t = 0; t < 4; t++) {
            uint2 pw;
            pw.x = pk2(s[t][0], s[t][1]);
            pw.y = pk2(s[t][2], s[t][3]);
            *(uint2*)&Pl[w][l15][t * 8 + hi * 2] = pw;
        }
        bf16x8 pb0 = *(const bf16x8*)&Pl[w][l15][hi * 4];
        bf16x8 pb1 = *(const bf16x8*)&Pl[w][l15][16 + hi * 4];

        // PV swapped: acc[d][q] += V^T[d][k] * P[q][k]
        acc0 = __builtin_amdgcn_mfma_f32_16x16x32_bf16(va, pb0, acc0, 0, 0, 0);
        acc1 = __builtin_amdgcn_mfma_f32_16x16x32_bf16(vb, pb0, acc1, 0, 0, 0);
        acc0 = __builtin_amdgcn_mfma_f32_16x16x32_bf16(vc, pb1, acc0, 0, 0, 0);
        acc1 = __builtin_amdgcn_mfma_f32_16x16x32_bf16(vd, pb1, acc1, 0, 0, 0);

        if (nkb < 0) break;
        kb = nkb;
        kc0 = kn0; kc1 = kn1; kc2 = kn2; kc3 = kn3;
    }

    float lsum = l_run;
    lsum += __shfl_xor(lsum, 16);
    lsum += __shfl_xor(lsum, 32);

    if (!is_cls) {
        float inv = 1.f / lsum;
        int wh = (qb / 7) * 8, wwc = (qb % 7) * 8;
        int inner = w * 16 + l15;
        int h0 = wh + (inner >> 3), w0 = wwc + (inner & 7);
        int c0 = head * HD + hi * 4;
        float u0[4], u1[4];
        #pragma unroll
        for (int r = 0; r < 4; r++) {
            u0[r] = acc0[r] * inv + lepe_b[c0 + r];
            u1[r] = acc1[r] * inv + lepe_b[c0 + 16 + r];
        }
        #pragma unroll
        for (int dh = -1; dh <= 1; dh++) {
            int h2 = h0 + dh;
            if (h2 < 0 || h2 >= Himg) continue;
            #pragma unroll
            for (int dw = -1; dw <= 1; dw++) {
                int w2 = w0 + dw;
                if (w2 < 0 || w2 >= Wimg) continue;
                long vbase = ((long)b * SIMG + h2 * Wimg + w2) * CC;
                int j = (dh + 1) * 3 + (dw + 1);
                ushort4 v0 = *(const ushort4*)&Vsp[vbase + c0];
                ushort4 v1 = *(const ushort4*)&Vsp[vbase + c0 + 16];
                float4 g0 = *(const float4*)&lepe_w[j * CC + c0];
                float4 g1 = *(const float4*)&lepe_w[j * CC + c0 + 16];
                u0[0] += bf2f(v0.x) * g0.x; u0[1] += bf2f(v0.y) * g0.y;
                u0[2] += bf2f(v0.z) * g0.z; u0[3] += bf2f(v0.w) * g0.w;
                u1[0] += bf2f(v1.x) * g1.x; u1[1] += bf2f(v1.y) * g1.y;
                u1[2] += bf2f(v1.z) * g1.z; u1[3] += bf2f(v1.w) * g1.w;
            }
        }
        long ubase = ((long)(b * SS + h0 * Wimg + w0)) * CC + c0;
        ushort4 o0, o1;
        o0.x = (unsigned short)f2bf(u0[0]); o0.y = (unsigned short)f2bf(u0[1]);
        o0.z = (unsigned short)f2bf(u0[2]); o0.w = (unsigned short)f2bf(u0[3]);
        o1.x = (unsigned short)f2bf(u1[0]); o1.y = (unsigned short)f2bf(u1[1]);
        o1.z = (unsigned short)f2bf(u1[2]); o1.w = (unsigned short)f2bf(u1[3]);
        *(ushort4*)&U[ubase]      = o0;
        *(ushort4*)&U[ubase + 16] = o1;
    } else {
        if (hi == 0) Ls[w][l15] = lsum;
        #pragma unroll
        for (int r = 0; r < 4; r++) {
            MAcc[w][l15][hi * 4 + r]      = acc0[r];
            MAcc[w][l15][16 + hi * 4 + r] = acc1[r];
        }
        __syncthreads();
        if (w == 0) {
            float L = Ls[0][l15] + Ls[1][l15] + Ls[2][l15] + Ls[3][l15];
            float o0[4] = {0.f, 0.f, 0.f, 0.f}, o1[4] = {0.f, 0.f, 0.f, 0.f};
            #pragma unroll
            for (int ww = 0; ww < 4; ww++) {
                #pragma unroll
                for (int r = 0; r < 4; r++) {
                    o0[r] += MAcc[ww][l15][hi * 4 + r];
                    o1[r] += MAcc[ww][l15][16 + hi * 4 + r];
                }
            }
            if (l15 < NQtok) {
                float invL = 1.f / L;
                long ubase = ((long)(b * SS + SIMG + l15)) * CC + head * HD + hi * 4;
                ushort4 q0, q1;
                q0.x = (unsigned short)f2bf(o0[0] * invL);
                q0.y = (unsigned short)f2bf(o0[1] * invL);
                q0.z = (unsigned short)f2bf(o0[2] * invL);
                q0.w = (unsigned short)f2bf(o0[3] * invL);
                q1.x = (unsigned short)f2bf(o1[0] * invL);
                q1.y = (unsigned short)f2bf(o1[1] * invL);
                q1.z = (unsigned short)f2bf(o1[2] * invL);
                q1.w = (unsigned short)f2bf(o1[3] * invL);
                *(ushort4*)&U[ubase]      = q0;
                *(ushort4*)&U[ubase + 16] = q1;
            }
        }
    }
}

// ---------------------------------------------------------------- out GEMM (fused Wo prep)
// 128-row blocks; block stages its Wo^T column tile into LDS; U read direct.
__global__ __launch_bounds__(256, 2) void out_fused(
        const short* __restrict__ U, const float* __restrict__ Wo,
        const float* __restrict__ bo, float* __restrict__ out) {
    __shared__ __align__(16) short Wl[64][264];
    int tid = threadIdx.x;
    int w = tid >> 6, l = tid & 63, l15 = l & 15, hi = l >> 4;
    int row0 = blockIdx.x * 128 + w * 32;
    int n0 = blockIdx.y * 64;

    stage_wt(Wo, 256, n0, tid, Wl);
    __syncthreads();

    f32x4 acc[2][4];
    #pragma unroll
    for (int rs = 0; rs < 2; rs++)
        #pragma unroll
        for (int t = 0; t < 4; t++) acc[rs][t] = (f32x4){0.f, 0.f, 0.f, 0.f};
    const short* Ap0 = U + (long)(row0 + l15) * CC + hi * 8;
    const short* Ap1 = Ap0 + 16 * CC;
    #pragma unroll
    for (int k0 = 0; k0 < 256; k0 += 32) {
        bf16x8 a0 = *(const bf16x8*)(Ap0 + k0);
        bf16x8 a1 = *(const bf16x8*)(Ap1 + k0);
        #pragma unroll
        for (int t = 0; t < 4; t++) {
            bf16x8 bf = *(const bf16x8*)&Wl[t * 16 + l15][k0 + hi * 8];
            acc[0][t] = __builtin_amdgcn_mfma_f32_16x16x32_bf16(a0, bf, acc[0][t], 0, 0, 0);
            acc[1][t] = __builtin_amdgcn_mfma_f32_16x16x32_bf16(a1, bf, acc[1][t], 0, 0, 0);
        }
    }
    float bias[4];
    #pragma unroll
    for (int t = 0; t < 4; t++) bias[t] = bo[n0 + t * 16 + l15];
    #pragma unroll
    for (int rs = 0; rs < 2; rs++) {
        #pragma unroll
        for (int r = 0; r < 4; r++) {
            int row = row0 + rs * 16 + hi * 4 + r;
            if (row >= NROWS) continue;
            int b = (row >= SS) ? 1 : 0;
            int tok = row - b * SS;
            long base;
            if (tok < SIMG) base = (long)(b * SIMG + tok) * CC;
            else base = (long)Bsz * SIMG * CC + (long)(b * NQtok + tok - SIMG) * CC;
            #pragma unroll
            for (int t = 0; t < 4; t++)
                out[base + n0 + t * 16 + l15] = acc[rs][t][r] + bias[t];
        }
    }
}

// ---------------------------------------------------------------- launch
extern "C" void kernel_launch(void* const* d_in, const int* in_sizes, int n_in,
                              void* d_out, int out_size, void* d_ws, size_t ws_size,
                              hipStream_t stream) {
    const float* x      = (const float*)d_in[0];
    const float* cls    = (const float*)d_in[1];
    const unsigned char* mask_raw = (const unsigned char*)d_in[2];
    const float* Wqkv   = (const float*)d_in[3];
    const float* bqkv   = (const float*)d_in[4];
    const float* lepe_w = (const float*)d_in[5];
    const float* lepe_b = (const float*)d_in[6];
    const float* Wo     = (const float*)d_in[7];
    const float* bo     = (const float*)d_in[8];
    float* out = (float*)d_out;

    short* Qbf = (short*)d_ws;
    short* Kbf = Qbf + QSZ;
    short* Vtb = Kbf + QSZ;
    short* U   = Vtb + QSZ;
    short* Vsp = U + USZ;

    qkv_fused<<<dim3(MROWS / 64, 12), 256, 0, stream>>>(x, cls, Wqkv, bqkv, Qbf, Kbf, Vtb, Vsp);
    attn_mfma<<<Bsz * NHd * NWIN, 256, 0, stream>>>(Qbf, Kbf, Vtb, Vsp, lepe_w, lepe_b, mask_raw, U);
    out_fused<<<dim3(MROWS / 128, 4), 256, 0, stream>>>(U, Wo, bo, out);
}